// Round 1
// baseline (338.012 us; speedup 1.0000x reference)
//
#include <hip/hip_runtime.h>
#include <hip/hip_bf16.h>

// BEVFormerLite: project BEV grid into 6 cameras, bilinear-sample features,
// average over valid cams, then 1x1 conv + BN + ReLU.
// B=4 N=6 C=256 fH=29 fW=50, BEV 200x200 (P=40000). Output (4,256,200,200) f32.
//
// Pipeline:
//  k0 prep:      24x (3x3 inverse + K@invR) -> 12 proj params per (b,cam);
//                fold BN+bias into per-o scale/bias; convert W to bf16.
//  k1 transpose: feats (b,n,c,y,x) f32 -> ft (b,n,y,x,c) bf16   [channel-last]
//  k2 sample:    per (b, 4 points) block, thread=channel; uniform-branch
//                validity; bilinear gather from ft; bev[b,p,c] bf16.
//  k3 gemm:      out[b,o,p] = relu(scale[o]*sum_c W[o,c]*bev[b,p,c] + bias[o])
//                MFMA 16x16x32 bf16, 64x64 tile, 4 waves.

#define P_TOT  40000
#define FH     29
#define FW     50
#define NCAM   6

typedef short bf16x8 __attribute__((ext_vector_type(8)));
typedef float f32x4  __attribute__((ext_vector_type(4)));

__device__ __forceinline__ float bf2f(unsigned short u) {
    union { unsigned int i; float f; } x; x.i = ((unsigned int)u) << 16; return x.f;
}
__device__ __forceinline__ unsigned short f2bf(float f) {
    union { float f; unsigned int i; } x; x.f = f;
    unsigned int i = x.i;
    return (unsigned short)((i + 0x7FFFu + ((i >> 16) & 1u)) >> 16);  // RNE
}

// ---------------- k0: geometry + BN fold + W->bf16 ----------------
__global__ void prep_kernel(const float* __restrict__ K, const float* __restrict__ E,
                            const float* __restrict__ convw, const float* __restrict__ convb,
                            const float* __restrict__ gamma, const float* __restrict__ beta,
                            const float* __restrict__ mean, const float* __restrict__ var,
                            float* __restrict__ params, float* __restrict__ sb,
                            unsigned short* __restrict__ wbf) {
    int idx = blockIdx.x * 256 + threadIdx.x;      // 256 blocks * 256 = 65536 = C*C
    wbf[idx] = f2bf(convw[idx]);
    if (blockIdx.x != 0) return;
    int o = threadIdx.x;
    // BN fold: y = g*(x + cb - mu)*rstd + be = x*s + bo
    float rstd = rsqrtf(var[o] + 1e-5f);
    float s = gamma[o] * rstd;
    sb[o]       = s;
    sb[256 + o] = (convb[o] - mean[o]) * s + beta[o];
    if (o >= 24) return;
    const float* e = E + o * 16;   // (b*6+n) row-major 4x4
    const float* k = K + o * 9;
    float a00=e[0], a01=e[1], a02=e[2],  t0=e[3];
    float a10=e[4], a11=e[5], a12=e[6],  t1=e[7];
    float a20=e[8], a21=e[9], a22=e[10], t2=e[11];
    float c00 =  (a11*a22 - a12*a21);
    float c01 = -(a10*a22 - a12*a20);
    float c02 =  (a10*a21 - a11*a20);
    float det = a00*c00 + a01*c01 + a02*c02;
    float id = 1.0f / det;
    // inv(R) = adj(R)/det  (adj = cofactor^T)
    float i00 =  c00*id;
    float i01 = -(a01*a22 - a02*a21)*id;
    float i02 =  (a01*a12 - a02*a11)*id;
    float i10 =  c01*id;
    float i11 =  (a00*a22 - a02*a20)*id;
    float i12 = -(a00*a12 - a02*a10)*id;
    float i20 =  c02*id;
    float i21 = -(a00*a21 - a01*a20)*id;
    float i22 =  (a00*a11 - a01*a10)*id;
    float tp0 = -(i00*t0 + i01*t1 + i02*t2);
    float tp1 = -(i10*t0 + i11*t1 + i12*t2);
    float tp2 = -(i20*t0 + i21*t1 + i22*t2);
    // M = K @ invR (only cols 0,1 needed since z=0), m = K @ t'
    float* q = params + o * 12;
    q[0] = k[0]*i00 + k[1]*i10 + k[2]*i20;   // M00
    q[1] = k[0]*i01 + k[1]*i11 + k[2]*i21;   // M01
    q[2] = k[0]*tp0 + k[1]*tp1 + k[2]*tp2;   // m0
    q[3] = k[3]*i00 + k[4]*i10 + k[5]*i20;   // M10
    q[4] = k[3]*i01 + k[4]*i11 + k[5]*i21;   // M11
    q[5] = k[3]*tp0 + k[4]*tp1 + k[5]*tp2;   // m1
    q[6] = k[6]*i00 + k[7]*i10 + k[8]*i20;   // M20
    q[7] = k[6]*i01 + k[7]*i11 + k[8]*i21;   // M21
    q[8] = k[6]*tp0 + k[7]*tp1 + k[8]*tp2;   // m2 (p_img z row)
    q[9]  = i20;                              // depth row
    q[10] = i21;
    q[11] = tp2;
}

// ---------------- k1: feats (bn,c,y,x) f32 -> ft (bn,y,x,c) bf16 ----------------
__global__ void transpose_kernel(const float* __restrict__ feats,
                                 unsigned short* __restrict__ ft) {
    int idx = blockIdx.x * 256 + threadIdx.x;   // total 4*6*29*50*256 = 8908800
    int c = idx & 255;
    int r = idx >> 8;            // (bn*29 + y)*50 + x
    int x = r % 50;
    int t = r / 50;
    int y = t % 29;
    int bn = t / 29;
    float v = feats[((bn * 256 + c) * FH + y) * FW + x];
    ft[idx] = f2bf(v);
}

// ---------------- k2: sample + average ----------------
__global__ __launch_bounds__(256) void sample_kernel(const unsigned short* __restrict__ ft,
                                                     const float* __restrict__ params,
                                                     unsigned short* __restrict__ bev) {
    int b  = blockIdx.y;
    int p0 = blockIdx.x * 4;
    int c  = threadIdx.x;
    float acc[4]  = {0.f, 0.f, 0.f, 0.f};
    float vsum[4] = {0.f, 0.f, 0.f, 0.f};
    for (int cam = 0; cam < NCAM; ++cam) {
        const float* q = params + (b * NCAM + cam) * 12;
        float q0=q[0], q1=q[1], q2=q[2], q3=q[3], q4=q[4], q5=q[5];
        float q6=q[6], q7=q[7], q8=q[8], q9=q[9], q10=q[10], q11=q[11];
        const unsigned short* base = ft + (size_t)(b * NCAM + cam) * FH * FW * 256;
        #pragma unroll
        for (int pt = 0; pt < 4; ++pt) {
            int p = p0 + pt;
            float gx = -49.75f + 0.5f * (float)(p % 200);
            float gy = -49.75f + 0.5f * (float)(p / 200);
            float wh    = q6 * gx + q7  * gy + q8;
            float depth = q9 * gx + q10 * gy + q11;
            float inv = 1.0f / (wh + 1e-6f);
            float u = (q0 * gx + q1 * gy + q2) * inv;
            float v = (q3 * gx + q4 * gy + q5) * inv;
            float uf = u * (50.0f / 1600.0f);
            float vf = v * (29.0f / 928.0f);
            float un = uf * (2.0f / 49.0f) - 1.0f;
            float vn = vf * (2.0f / 28.0f) - 1.0f;
            if (!(depth > 0.1f && un >= -1.0f && un <= 1.0f &&
                                  vn >= -1.0f && vn <= 1.0f)) continue;
            float xs = (un + 1.0f) * 0.5f * 49.0f;
            float ys = (vn + 1.0f) * 0.5f * 28.0f;
            float x0f = floorf(xs), y0f = floorf(ys);
            float wx = xs - x0f, wy = ys - y0f;
            int x0 = (int)x0f, y0 = (int)y0f;
            int x1 = x0 + 1,  y1 = y0 + 1;
            // valid => xs in [0,49], ys in [0,28] => (x0,y0) always in range
            float v00 = bf2f(base[(y0 * FW + x0) * 256 + c]);
            float v01 = 0.f, v10 = 0.f, v11 = 0.f;
            bool okx = (x1 <= FW - 1), oky = (y1 <= FH - 1);
            if (okx)        v01 = bf2f(base[(y0 * FW + x1) * 256 + c]);
            if (oky)        v10 = bf2f(base[(y1 * FW + x0) * 256 + c]);
            if (okx && oky) v11 = bf2f(base[(y1 * FW + x1) * 256 + c]);
            acc[pt] += v00 * (1.f - wx) * (1.f - wy) + v01 * wx * (1.f - wy)
                     + v10 * (1.f - wx) * wy         + v11 * wx * wy;
            vsum[pt] += 1.0f;
        }
    }
    #pragma unroll
    for (int pt = 0; pt < 4; ++pt) {
        int p = p0 + pt;
        bev[((size_t)b * P_TOT + p) * 256 + c] = f2bf(acc[pt] / (vsum[pt] + 1e-6f));
    }
}

// ---------------- k3: GEMM out[o,p] = relu(s[o]*sum_c W[o,c]*bev[p,c] + bo[o]) ----------------
__global__ __launch_bounds__(256) void gemm_kernel(const unsigned short* __restrict__ wbf,
                                                   const unsigned short* __restrict__ bev,
                                                   const float* __restrict__ sb,
                                                   float* __restrict__ out) {
    __shared__ unsigned short Wt[64][40];   // 32 k + 8 pad (80B row stride, 16B aligned)
    __shared__ unsigned short Bt[64][40];
    int obase = blockIdx.x * 64;            // 4 o-tiles (fastest: bev tile L2 reuse)
    int pbase = blockIdx.y * 64;            // 625 p-tiles
    int b     = blockIdx.z;
    int tid  = threadIdx.x;
    int lane = tid & 63;
    int wv   = tid >> 6;
    int lrow = tid >> 2;                    // 0..63
    int lk   = (tid & 3) * 8;               // 0,8,16,24
    const unsigned short* wsrc = wbf + (size_t)(obase + lrow) * 256 + lk;
    const unsigned short* bsrc = bev + ((size_t)b * P_TOT + pbase + lrow) * 256 + lk;
    f32x4 acc[4];
    #pragma unroll
    for (int nf = 0; nf < 4; ++nf) acc[nf] = (f32x4){0.f, 0.f, 0.f, 0.f};
    int arow = wv * 16 + (lane & 15);
    int kq   = (lane >> 4) * 8;
    for (int kt = 0; kt < 8; ++kt) {
        *(uint4*)&Wt[lrow][lk] = *(const uint4*)(wsrc + kt * 32);
        *(uint4*)&Bt[lrow][lk] = *(const uint4*)(bsrc + kt * 32);
        __syncthreads();
        bf16x8 a = *(const bf16x8*)&Wt[arow][kq];
        #pragma unroll
        for (int nf = 0; nf < 4; ++nf) {
            bf16x8 bb = *(const bf16x8*)&Bt[nf * 16 + (lane & 15)][kq];
            acc[nf] = __builtin_amdgcn_mfma_f32_16x16x32_bf16(a, bb, acc[nf], 0, 0, 0);
        }
        __syncthreads();
    }
    int colp = pbase + (lane & 15);
    #pragma unroll
    for (int nf = 0; nf < 4; ++nf) {
        #pragma unroll
        for (int r = 0; r < 4; ++r) {
            int o = obase + wv * 16 + (lane >> 4) * 4 + r;
            int p = colp + nf * 16;
            float y = acc[nf][r] * sb[o] + sb[256 + o];
            out[((size_t)b * 256 + o) * P_TOT + p] = fmaxf(y, 0.0f);
        }
    }
}

extern "C" void kernel_launch(void* const* d_in, const int* in_sizes, int n_in,
                              void* d_out, int out_size, void* d_ws, size_t ws_size,
                              hipStream_t stream) {
    const float* feats = (const float*)d_in[0];
    const float* intr  = (const float*)d_in[1];
    const float* extr  = (const float*)d_in[2];
    const float* convw = (const float*)d_in[3];
    const float* convb = (const float*)d_in[4];
    const float* gamma = (const float*)d_in[5];
    const float* beta  = (const float*)d_in[6];
    const float* mean  = (const float*)d_in[7];
    const float* var   = (const float*)d_in[8];

    char* ws = (char*)d_ws;
    float*          params = (float*)(ws + 0);          // 24*12*4 = 1152 B
    float*          sb     = (float*)(ws + 2048);       // 2*256*4 = 2 KB
    unsigned short* wbf    = (unsigned short*)(ws + 4096);      // 65536*2 = 128 KB
    unsigned short* ft     = (unsigned short*)(ws + 135168);    // 8908800*2 = 17.0 MB
    unsigned short* bev    = (unsigned short*)(ws + 17952768);  // 4*40000*256*2 = 78.1 MB
    float* out = (float*)d_out;

    hipLaunchKernelGGL(prep_kernel, dim3(256), dim3(256), 0, stream,
                       intr, extr, convw, convb, gamma, beta, mean, var, params, sb, wbf);
    hipLaunchKernelGGL(transpose_kernel, dim3(34800), dim3(256), 0, stream, feats, ft);
    hipLaunchKernelGGL(sample_kernel, dim3(10000, 4), dim3(256), 0, stream, ft, params, bev);
    hipLaunchKernelGGL(gemm_kernel, dim3(4, 625, 4), dim3(256), 0, stream, wbf, bev, sb, out);
}

// Round 2
// 153.135 us; speedup vs baseline: 2.2073x; 2.2073x over previous
//
#include <hip/hip_runtime.h>
#include <hip/hip_bf16.h>

// BEVFormerLite: project BEV grid into 6 cameras, bilinear-sample features,
// average over valid cams, then 1x1 conv + BN + ReLU.
// B=4 N=6 C=256 fH=29 fW=50, BEV 200x200 (P=40000). Output (4,256,200,200) f32.
//
// Pipeline (round 2: descriptor-based sampling — projection math once per
// (b,p,cam) instead of once per channel-thread; sampler is pure gather+FMA):
//  k0 prep:      geometry -> 12 proj params per (b,cam); BN fold; W->bf16.
//  k1 transpose: feats (b,n,c,y,x) f32 -> ft (b,n,y,x,c) bf16  [channel-last]
//  k2 prep2:     per (b,p): valid cams -> compacted {4 corner offsets, 4
//                weights} descriptors + count + 1/(count+eps).  (in d_out!)
//  k3 sample2:   one wave per point; lane = 4 channels (ushort4 loads);
//                loop count slots: 4 gathers + FMAs. bev[b,p,c] bf16.
//  k4 gemm:      out[b,o,p] = relu(s[o]*sum_c W[o,c]*bev[b,p,c] + bo[o])
//                MFMA 16x16x32 bf16, 64x64 tile, 4 waves.

#define P_TOT  40000
#define FH     29
#define FW     50
#define NCAM   6

typedef short bf16x8 __attribute__((ext_vector_type(8)));
typedef float f32x4  __attribute__((ext_vector_type(4)));
typedef unsigned short u16x4 __attribute__((ext_vector_type(4)));

struct Desc { int off00, off01, off10, off11; float w00, w01, w10, w11; };

__device__ __forceinline__ float bf2f(unsigned short u) {
    union { unsigned int i; float f; } x; x.i = ((unsigned int)u) << 16; return x.f;
}
__device__ __forceinline__ unsigned short f2bf(float f) {
    union { float f; unsigned int i; } x; x.f = f;
    unsigned int i = x.i;
    return (unsigned short)((i + 0x7FFFu + ((i >> 16) & 1u)) >> 16);  // RNE
}

// ---------------- k0: geometry + BN fold + W->bf16 ----------------
__global__ void prep_kernel(const float* __restrict__ K, const float* __restrict__ E,
                            const float* __restrict__ convw, const float* __restrict__ convb,
                            const float* __restrict__ gamma, const float* __restrict__ beta,
                            const float* __restrict__ mean, const float* __restrict__ var,
                            float* __restrict__ params, float* __restrict__ sb,
                            unsigned short* __restrict__ wbf) {
    int idx = blockIdx.x * 256 + threadIdx.x;      // 256 blocks * 256 = 65536 = C*C
    wbf[idx] = f2bf(convw[idx]);
    if (blockIdx.x != 0) return;
    int o = threadIdx.x;
    float rstd = rsqrtf(var[o] + 1e-5f);
    float s = gamma[o] * rstd;
    sb[o]       = s;
    sb[256 + o] = (convb[o] - mean[o]) * s + beta[o];
    if (o >= 24) return;
    const float* e = E + o * 16;
    const float* k = K + o * 9;
    float a00=e[0], a01=e[1], a02=e[2],  t0=e[3];
    float a10=e[4], a11=e[5], a12=e[6],  t1=e[7];
    float a20=e[8], a21=e[9], a22=e[10], t2=e[11];
    float c00 =  (a11*a22 - a12*a21);
    float c01 = -(a10*a22 - a12*a20);
    float c02 =  (a10*a21 - a11*a20);
    float det = a00*c00 + a01*c01 + a02*c02;
    float id = 1.0f / det;
    float i00 =  c00*id;
    float i01 = -(a01*a22 - a02*a21)*id;
    float i02 =  (a01*a12 - a02*a11)*id;
    float i10 =  c01*id;
    float i11 =  (a00*a22 - a02*a20)*id;
    float i12 = -(a00*a12 - a02*a10)*id;
    float i20 =  c02*id;
    float i21 = -(a00*a21 - a01*a20)*id;
    float i22 =  (a00*a11 - a01*a10)*id;
    float tp0 = -(i00*t0 + i01*t1 + i02*t2);
    float tp1 = -(i10*t0 + i11*t1 + i12*t2);
    float tp2 = -(i20*t0 + i21*t1 + i22*t2);
    float* q = params + o * 12;
    q[0] = k[0]*i00 + k[1]*i10 + k[2]*i20;
    q[1] = k[0]*i01 + k[1]*i11 + k[2]*i21;
    q[2] = k[0]*tp0 + k[1]*tp1 + k[2]*tp2;
    q[3] = k[3]*i00 + k[4]*i10 + k[5]*i20;
    q[4] = k[3]*i01 + k[4]*i11 + k[5]*i21;
    q[5] = k[3]*tp0 + k[4]*tp1 + k[5]*tp2;
    q[6] = k[6]*i00 + k[7]*i10 + k[8]*i20;
    q[7] = k[6]*i01 + k[7]*i11 + k[8]*i21;
    q[8] = k[6]*tp0 + k[7]*tp1 + k[8]*tp2;
    q[9]  = i20;
    q[10] = i21;
    q[11] = tp2;
}

// ---------------- k1: feats (bn,c,y,x) f32 -> ft (bn,y,x,c) bf16 ----------------
__global__ void transpose_kernel(const float* __restrict__ feats,
                                 unsigned short* __restrict__ ft) {
    int idx = blockIdx.x * 256 + threadIdx.x;   // total 4*6*29*50*256 = 8908800
    int c = idx & 255;
    int r = idx >> 8;
    int x = r % 50;
    int t = r / 50;
    int y = t % 29;
    int bn = t / 29;
    float v = feats[((bn * 256 + c) * FH + y) * FW + x];
    ft[idx] = f2bf(v);
}

// ---------------- k2: per-(b,p) projection -> compacted descriptors ----------------
__global__ __launch_bounds__(256) void prep2_kernel(const float* __restrict__ params,
                                                    Desc* __restrict__ desc,
                                                    int* __restrict__ cnt,
                                                    float* __restrict__ scale) {
    int idx = blockIdx.x * 256 + threadIdx.x;   // 625*256 = 160000 = B*P
    int b = idx / P_TOT;
    int p = idx - b * P_TOT;
    float gx = -49.75f + 0.5f * (float)(p % 200);
    float gy = -49.75f + 0.5f * (float)(p / 200);
    int c = 0;
    Desc* dp = desc + (size_t)idx * NCAM;
    for (int cam = 0; cam < NCAM; ++cam) {
        const float* q = params + (b * NCAM + cam) * 12;
        float wh    = q[6] * gx + q[7]  * gy + q[8];
        float depth = q[9] * gx + q[10] * gy + q[11];
        float inv = 1.0f / (wh + 1e-6f);
        float u = (q[0] * gx + q[1] * gy + q[2]) * inv;
        float v = (q[3] * gx + q[4] * gy + q[5]) * inv;
        float un = u * (50.0f / 1600.0f) * (2.0f / 49.0f) - 1.0f;
        float vn = v * (29.0f / 928.0f)  * (2.0f / 28.0f) - 1.0f;
        if (!(depth > 0.1f && un >= -1.0f && un <= 1.0f &&
                              vn >= -1.0f && vn <= 1.0f)) continue;
        float xs = (un + 1.0f) * 0.5f * 49.0f;
        float ys = (vn + 1.0f) * 0.5f * 28.0f;
        float x0f = floorf(xs), y0f = floorf(ys);
        float wx = xs - x0f, wy = ys - y0f;
        int x0 = (int)x0f, y0 = (int)y0f;
        bool okx = (x0 < FW - 1), oky = (y0 < FH - 1);
        int base = (((b * NCAM + cam) * FH + y0) * FW + x0) * 256;
        Desc d;
        d.off00 = base;
        d.off01 = base + (okx ? 256 : 0);
        d.off10 = base + (oky ? FW * 256 : 0);
        d.off11 = d.off10 + (okx ? 256 : 0);
        float iwx = 1.0f - wx, iwy = 1.0f - wy;
        d.w00 = iwx * iwy;
        d.w01 = okx ? wx * iwy : 0.0f;
        d.w10 = oky ? iwx * wy : 0.0f;
        d.w11 = (okx && oky) ? wx * wy : 0.0f;
        dp[c] = d;
        ++c;
    }
    cnt[idx] = c;
    scale[idx] = 1.0f / ((float)c + 1e-6f);
}

// ---------------- k3: sample + average (one wave per point, lane = 4 channels) ----------------
__global__ __launch_bounds__(256) void sample2_kernel(const unsigned short* __restrict__ ft,
                                                      const Desc* __restrict__ desc,
                                                      const int* __restrict__ cnt,
                                                      const float* __restrict__ scale,
                                                      unsigned short* __restrict__ bev) {
    int b    = blockIdx.y;
    int p    = blockIdx.x * 4 + (threadIdx.x >> 6);
    int lane = threadIdx.x & 63;
    int bp   = b * P_TOT + p;
    int ch   = lane * 4;
    int n = cnt[bp];
    float sc = scale[bp];
    float a0 = 0.f, a1 = 0.f, a2 = 0.f, a3 = 0.f;
    const Desc* dp = desc + (size_t)bp * NCAM;
    for (int s = 0; s < n; ++s) {
        Desc d = dp[s];
        u16x4 v;
        v = *(const u16x4*)(ft + d.off00 + ch);
        a0 += d.w00 * bf2f(v[0]); a1 += d.w00 * bf2f(v[1]);
        a2 += d.w00 * bf2f(v[2]); a3 += d.w00 * bf2f(v[3]);
        v = *(const u16x4*)(ft + d.off01 + ch);
        a0 += d.w01 * bf2f(v[0]); a1 += d.w01 * bf2f(v[1]);
        a2 += d.w01 * bf2f(v[2]); a3 += d.w01 * bf2f(v[3]);
        v = *(const u16x4*)(ft + d.off10 + ch);
        a0 += d.w10 * bf2f(v[0]); a1 += d.w10 * bf2f(v[1]);
        a2 += d.w10 * bf2f(v[2]); a3 += d.w10 * bf2f(v[3]);
        v = *(const u16x4*)(ft + d.off11 + ch);
        a0 += d.w11 * bf2f(v[0]); a1 += d.w11 * bf2f(v[1]);
        a2 += d.w11 * bf2f(v[2]); a3 += d.w11 * bf2f(v[3]);
    }
    u16x4 o;
    o[0] = f2bf(a0 * sc); o[1] = f2bf(a1 * sc);
    o[2] = f2bf(a2 * sc); o[3] = f2bf(a3 * sc);
    *(u16x4*)(bev + (size_t)bp * 256 + ch) = o;
}

// ---------------- k4: GEMM out[o,p] = relu(s[o]*sum_c W[o,c]*bev[p,c] + bo[o]) ----------------
__global__ __launch_bounds__(256) void gemm_kernel(const unsigned short* __restrict__ wbf,
                                                   const unsigned short* __restrict__ bev,
                                                   const float* __restrict__ sb,
                                                   float* __restrict__ out) {
    __shared__ unsigned short Wt[64][40];
    __shared__ unsigned short Bt[64][40];
    int obase = blockIdx.x * 64;
    int pbase = blockIdx.y * 64;
    int b     = blockIdx.z;
    int tid  = threadIdx.x;
    int lane = tid & 63;
    int wv   = tid >> 6;
    int lrow = tid >> 2;
    int lk   = (tid & 3) * 8;
    const unsigned short* wsrc = wbf + (size_t)(obase + lrow) * 256 + lk;
    const unsigned short* bsrc = bev + ((size_t)b * P_TOT + pbase + lrow) * 256 + lk;
    f32x4 acc[4];
    #pragma unroll
    for (int nf = 0; nf < 4; ++nf) acc[nf] = (f32x4){0.f, 0.f, 0.f, 0.f};
    int arow = wv * 16 + (lane & 15);
    int kq   = (lane >> 4) * 8;
    for (int kt = 0; kt < 8; ++kt) {
        *(uint4*)&Wt[lrow][lk] = *(const uint4*)(wsrc + kt * 32);
        *(uint4*)&Bt[lrow][lk] = *(const uint4*)(bsrc + kt * 32);
        __syncthreads();
        bf16x8 a = *(const bf16x8*)&Wt[arow][kq];
        #pragma unroll
        for (int nf = 0; nf < 4; ++nf) {
            bf16x8 bb = *(const bf16x8*)&Bt[nf * 16 + (lane & 15)][kq];
            acc[nf] = __builtin_amdgcn_mfma_f32_16x16x32_bf16(a, bb, acc[nf], 0, 0, 0);
        }
        __syncthreads();
    }
    int colp = pbase + (lane & 15);
    #pragma unroll
    for (int nf = 0; nf < 4; ++nf) {
        #pragma unroll
        for (int r = 0; r < 4; ++r) {
            int o = obase + wv * 16 + (lane >> 4) * 4 + r;
            int p = colp + nf * 16;
            float y = acc[nf][r] * sb[o] + sb[256 + o];
            out[((size_t)b * 256 + o) * P_TOT + p] = fmaxf(y, 0.0f);
        }
    }
}

extern "C" void kernel_launch(void* const* d_in, const int* in_sizes, int n_in,
                              void* d_out, int out_size, void* d_ws, size_t ws_size,
                              hipStream_t stream) {
    const float* feats = (const float*)d_in[0];
    const float* intr  = (const float*)d_in[1];
    const float* extr  = (const float*)d_in[2];
    const float* convw = (const float*)d_in[3];
    const float* convb = (const float*)d_in[4];
    const float* gamma = (const float*)d_in[5];
    const float* beta  = (const float*)d_in[6];
    const float* mean  = (const float*)d_in[7];
    const float* var   = (const float*)d_in[8];

    char* ws = (char*)d_ws;
    float*          params = (float*)(ws + 0);          // 1152 B
    float*          sb     = (float*)(ws + 2048);       // 2 KB
    unsigned short* wbf    = (unsigned short*)(ws + 4096);      // 128 KB
    unsigned short* ft     = (unsigned short*)(ws + 135168);    // 17.0 MB
    unsigned short* bev    = (unsigned short*)(ws + 17952768);  // 78.1 MB

    // Descriptors live in d_out (164 MB): consumed by sample2 before gemm
    // (stream-ordered) and fully overwritten by gemm afterwards.
    char* outc = (char*)d_out;
    Desc*  desc   = (Desc*)outc;                        // 160000*6*32 = 30.7 MB
    int*   cnt    = (int*)(outc + 32 * 1024 * 1024);    // 640 KB
    float* scale  = (float*)(outc + 34 * 1024 * 1024);  // 640 KB
    float* out    = (float*)d_out;

    hipLaunchKernelGGL(prep_kernel, dim3(256), dim3(256), 0, stream,
                       intr, extr, convw, convb, gamma, beta, mean, var, params, sb, wbf);
    hipLaunchKernelGGL(transpose_kernel, dim3(34800), dim3(256), 0, stream, feats, ft);
    hipLaunchKernelGGL(prep2_kernel, dim3(625), dim3(256), 0, stream, params, desc, cnt, scale);
    hipLaunchKernelGGL(sample2_kernel, dim3(10000, 4), dim3(256), 0, stream,
                       ft, desc, cnt, scale, bev);
    hipLaunchKernelGGL(gemm_kernel, dim3(4, 625, 4), dim3(256), 0, stream, wbf, bev, sb, out);
}

// Round 3
// 77.152 us; speedup vs baseline: 4.3811x; 1.9849x over previous
//
#include <hip/hip_runtime.h>
#include <hip/hip_bf16.h>

// BEVFormerLite fused: project BEV grid into 6 cameras, bilinear-sample,
// average valid cams, 1x1 conv + BN + ReLU.
// B=4 N=6 C=256 fH=29 fW=50, BEV 200x200 (P=40000). Output (4,256,200,200) f32.
//
// Round 3: single fused sample+GEMM kernel per (b, 64-point tile).
//  k0 prep:      geometry -> 12 proj params per (b,cam); BN fold; W->bf16.
//  k1 transpose: feats (b,n,c,y,x) f32 -> ft (b,n,y,x,c) bf16, LDS-tiled.
//  k2 fused:     phase A: in-block projection -> compacted 8B slots (LDS),
//                         stage W k-tile 0, preload scale/bias.
//                phase B: gather-sample 64 pts x 256 ch -> bev tile in LDS.
//                phase C: K=256 MFMA GEMM (bev x W^T) + BN + ReLU -> out.
//                bev and descriptors never touch HBM.

#define P_TOT  40000
#define FH     29
#define FW     50
#define NCAM   6

typedef short bf16x8 __attribute__((ext_vector_type(8)));
typedef float f32x4  __attribute__((ext_vector_type(4)));
typedef unsigned short u16x8 __attribute__((ext_vector_type(8)));

__device__ __forceinline__ float bf2f(unsigned short u) {
    union { unsigned int i; float f; } x; x.i = ((unsigned int)u) << 16; return x.f;
}
__device__ __forceinline__ unsigned short f2bf(float f) {
    union { float f; unsigned int i; } x; x.f = f;
    unsigned int i = x.i;
    return (unsigned short)((i + 0x7FFFu + ((i >> 16) & 1u)) >> 16);  // RNE
}

// ---------------- k0: geometry + BN fold + W->bf16 ----------------
__global__ void prep_kernel(const float* __restrict__ K, const float* __restrict__ E,
                            const float* __restrict__ convw, const float* __restrict__ convb,
                            const float* __restrict__ gamma, const float* __restrict__ beta,
                            const float* __restrict__ mean, const float* __restrict__ var,
                            float* __restrict__ params, float* __restrict__ sb,
                            unsigned short* __restrict__ wbf) {
    int idx = blockIdx.x * 256 + threadIdx.x;      // 256 blocks * 256 = 65536 = C*C
    wbf[idx] = f2bf(convw[idx]);
    if (blockIdx.x != 0) return;
    int o = threadIdx.x;
    float rstd = rsqrtf(var[o] + 1e-5f);
    float s = gamma[o] * rstd;
    sb[o]       = s;
    sb[256 + o] = (convb[o] - mean[o]) * s + beta[o];
    if (o >= 24) return;
    const float* e = E + o * 16;
    const float* k = K + o * 9;
    float a00=e[0], a01=e[1], a02=e[2],  t0=e[3];
    float a10=e[4], a11=e[5], a12=e[6],  t1=e[7];
    float a20=e[8], a21=e[9], a22=e[10], t2=e[11];
    float c00 =  (a11*a22 - a12*a21);
    float c01 = -(a10*a22 - a12*a20);
    float c02 =  (a10*a21 - a11*a20);
    float det = a00*c00 + a01*c01 + a02*c02;
    float id = 1.0f / det;
    float i00 =  c00*id;
    float i01 = -(a01*a22 - a02*a21)*id;
    float i02 =  (a01*a12 - a02*a11)*id;
    float i10 =  c01*id;
    float i11 =  (a00*a22 - a02*a20)*id;
    float i12 = -(a00*a12 - a02*a10)*id;
    float i20 =  c02*id;
    float i21 = -(a00*a21 - a01*a20)*id;
    float i22 =  (a00*a11 - a01*a10)*id;
    float tp0 = -(i00*t0 + i01*t1 + i02*t2);
    float tp1 = -(i10*t0 + i11*t1 + i12*t2);
    float tp2 = -(i20*t0 + i21*t1 + i22*t2);
    float* q = params + o * 12;
    q[0] = k[0]*i00 + k[1]*i10 + k[2]*i20;
    q[1] = k[0]*i01 + k[1]*i11 + k[2]*i21;
    q[2] = k[0]*tp0 + k[1]*tp1 + k[2]*tp2;
    q[3] = k[3]*i00 + k[4]*i10 + k[5]*i20;
    q[4] = k[3]*i01 + k[4]*i11 + k[5]*i21;
    q[5] = k[3]*tp0 + k[4]*tp1 + k[5]*tp2;
    q[6] = k[6]*i00 + k[7]*i10 + k[8]*i20;
    q[7] = k[6]*i01 + k[7]*i11 + k[8]*i21;
    q[8] = k[6]*tp0 + k[7]*tp1 + k[8]*tp2;
    q[9]  = i20;
    q[10] = i21;
    q[11] = tp2;
}

// ---------------- k1: LDS-tiled transpose, one (bn,y) row per block ----------------
__global__ __launch_bounds__(256) void transpose_kernel(const float* __restrict__ feats,
                                                        unsigned short* __restrict__ ft) {
    __shared__ unsigned short tile[256][58];   // pad 50->58: 116B stride, conflict-light
    int by = blockIdx.x;                       // bn*29 + y  (696 blocks)
    int t  = threadIdx.x;
    int bn = by / FH, y = by - bn * FH;
    const float* src = feats + (size_t)bn * 256 * FH * FW + y * FW;
    #pragma unroll
    for (int i = 0; i < 50; ++i) {             // reads: runs of 50 consecutive floats
        int flat = i * 256 + t;
        int c = flat / 50;
        int x = flat - c * 50;
        tile[c][x] = f2bf(src[c * FH * FW + x]);
    }
    __syncthreads();
    unsigned short* dst = ft + (size_t)by * 50 * 256;
    #pragma unroll
    for (int i = 0; i < 25; ++i) {             // writes: fully coalesced u32
        int flat = i * 512 + t * 2;
        int x = flat >> 8;
        int c = flat & 255;
        unsigned int v = (unsigned int)tile[c][x] | ((unsigned int)tile[c + 1][x] << 16);
        *(unsigned int*)(dst + x * 256 + c) = v;
    }
}

// ---------------- k2: fused sample + GEMM + BN + ReLU ----------------
__global__ __launch_bounds__(512, 4) void fused_kernel(const unsigned short* __restrict__ ft,
                                                       const float* __restrict__ params,
                                                       const unsigned short* __restrict__ wbf,
                                                       const float* __restrict__ sb,
                                                       float* __restrict__ out) {
    __shared__ unsigned short Bt[64][264];        // bev tile [p][c], 528B rows (2-way = free)
    __shared__ unsigned short Wt[2][256][40];     // W k-tiles [o][32k+8pad], double-buffered
    __shared__ int           sbf[64][6];          // slot: base|okx|oky, -1 = invalid
    __shared__ unsigned int  swxy[64][6];         // wx,wy as u16 fixed-point
    __shared__ int           scnt[64];
    __shared__ float         sscale[64];
    __shared__ float         ssb[512];            // scale[256] + bias[256]

    int tid   = threadIdx.x;
    int pbase = blockIdx.x * 64;
    int b     = blockIdx.y;

    ssb[tid] = sb[tid];

    // ---- stage W k-tile 0 ----
    {
        int row = tid >> 1, half = tid & 1;
        const unsigned short* s = wbf + row * 256 + half * 16;
        uint4 w0 = *(const uint4*)(s);
        uint4 w1 = *(const uint4*)(s + 8);
        *(uint4*)&Wt[0][row][half * 16]     = w0;
        *(uint4*)&Wt[0][row][half * 16 + 8] = w1;
    }

    // ---- phase A: projection, one thread per (point, cam) ----
    if (tid < 384) {
        int pt  = tid / 6;
        int cam = tid - pt * 6;
        int p   = pbase + pt;
        float gx = -49.75f + 0.5f * (float)(p % 200);
        float gy = -49.75f + 0.5f * (float)(p / 200);
        const float* q = params + (b * NCAM + cam) * 12;
        float wh    = q[6] * gx + q[7]  * gy + q[8];
        float depth = q[9] * gx + q[10] * gy + q[11];
        float inv = 1.0f / (wh + 1e-6f);
        float u = (q[0] * gx + q[1] * gy + q[2]) * inv;
        float v = (q[3] * gx + q[4] * gy + q[5]) * inv;
        float un = u * (50.0f / 1600.0f) * (2.0f / 49.0f) - 1.0f;
        float vn = v * (29.0f / 928.0f)  * (2.0f / 28.0f) - 1.0f;
        int bf = -1; unsigned int wxy = 0;
        if (depth > 0.1f && un >= -1.0f && un <= 1.0f &&
                            vn >= -1.0f && vn <= 1.0f) {
            float xs = (un + 1.0f) * 0.5f * 49.0f;
            float ys = (vn + 1.0f) * 0.5f * 28.0f;
            float x0f = floorf(xs), y0f = floorf(ys);
            float wx = xs - x0f, wy = ys - y0f;
            int x0 = (int)x0f, y0 = (int)y0f;
            int okx = (x0 < FW - 1) ? 1 : 0;
            int oky = (y0 < FH - 1) ? 2 : 0;
            int base = (((b * NCAM + cam) * FH + y0) * FW + x0) * 256; // low 8 bits free
            bf  = base | okx | oky;
            wxy = (unsigned int)(wx * 65535.0f + 0.5f)
                | ((unsigned int)(wy * 65535.0f + 0.5f) << 16);
        }
        sbf[pt][cam]  = bf;
        swxy[pt][cam] = wxy;
    }
    __syncthreads();

    // ---- compact slots per point (cam order preserved) ----
    if (tid < 64) {
        int c = 0;
        #pragma unroll
        for (int cam = 0; cam < NCAM; ++cam) {
            int v = sbf[tid][cam];
            unsigned int w = swxy[tid][cam];
            if (v >= 0) { sbf[tid][c] = v; swxy[tid][c] = w; ++c; }
        }
        scnt[tid]   = c;
        sscale[tid] = 1.0f / ((float)c + 1e-6f);
    }
    __syncthreads();

    // ---- phase B: sample, 8 threads/point x 32 channels ----
    {
        int pt = tid >> 3, sub = tid & 7, ch0 = sub * 32;
        float acc[32];
        #pragma unroll
        for (int j = 0; j < 32; ++j) acc[j] = 0.0f;
        int n = scnt[pt];
        for (int s = 0; s < n; ++s) {
            int bf = sbf[pt][s];
            unsigned int wxy = swxy[pt][s];
            int base = bf & ~255;
            int okx = bf & 1, oky = bf & 2;
            float wx = (float)(wxy & 0xffffu) * (1.0f / 65535.0f);
            float wy = (float)(wxy >> 16)     * (1.0f / 65535.0f);
            float iwx = 1.0f - wx, iwy = 1.0f - wy;
            float w00 = iwx * iwy;
            float w01 = okx ? wx * iwy : 0.0f;
            float w10 = oky ? iwx * wy : 0.0f;
            float w11 = (okx && oky) ? wx * wy : 0.0f;
            const unsigned short* p00 = ft + base + ch0;
            int o01 = okx ? 256 : 0;
            int o10 = oky ? FW * 256 : 0;
            #pragma unroll
            for (int qv = 0; qv < 4; ++qv) {
                u16x8 v0 = *(const u16x8*)(p00 + qv * 8);
                #pragma unroll
                for (int j = 0; j < 8; ++j) acc[qv * 8 + j] += w00 * bf2f(v0[j]);
            }
            #pragma unroll
            for (int qv = 0; qv < 4; ++qv) {
                u16x8 v1 = *(const u16x8*)(p00 + o01 + qv * 8);
                #pragma unroll
                for (int j = 0; j < 8; ++j) acc[qv * 8 + j] += w01 * bf2f(v1[j]);
            }
            #pragma unroll
            for (int qv = 0; qv < 4; ++qv) {
                u16x8 v2 = *(const u16x8*)(p00 + o10 + qv * 8);
                #pragma unroll
                for (int j = 0; j < 8; ++j) acc[qv * 8 + j] += w10 * bf2f(v2[j]);
            }
            #pragma unroll
            for (int qv = 0; qv < 4; ++qv) {
                u16x8 v3 = *(const u16x8*)(p00 + o10 + o01 + qv * 8);
                #pragma unroll
                for (int j = 0; j < 8; ++j) acc[qv * 8 + j] += w11 * bf2f(v3[j]);
            }
        }
        float sc = sscale[pt];
        #pragma unroll
        for (int qv = 0; qv < 4; ++qv) {
            u16x8 ov;
            #pragma unroll
            for (int j = 0; j < 8; ++j) ov[j] = f2bf(acc[qv * 8 + j] * sc);
            *(u16x8*)&Bt[pt][ch0 + qv * 8] = ov;
        }
    }
    __syncthreads();

    // ---- phase C: GEMM, 8 waves x (32o x 64p), K=256 in 8 steps ----
    int lane = tid & 63, wv = tid >> 6;
    f32x4 acc2[2][4];
    #pragma unroll
    for (int f = 0; f < 2; ++f)
        #pragma unroll
        for (int nf = 0; nf < 4; ++nf) acc2[f][nf] = (f32x4){0.f, 0.f, 0.f, 0.f};
    int arow = wv * 32 + (lane & 15);
    int kq   = (lane >> 4) * 8;
    int srow = tid >> 1, shalf = tid & 1;
    for (int kt = 0; kt < 8; ++kt) {
        uint4 w0, w1;
        if (kt < 7) {   // prefetch next W k-tile while computing
            const unsigned short* s = wbf + srow * 256 + (kt + 1) * 32 + shalf * 16;
            w0 = *(const uint4*)(s);
            w1 = *(const uint4*)(s + 8);
        }
        bf16x8 a0 = *(const bf16x8*)&Wt[kt & 1][arow][kq];
        bf16x8 a1 = *(const bf16x8*)&Wt[kt & 1][arow + 16][kq];
        #pragma unroll
        for (int nf = 0; nf < 4; ++nf) {
            bf16x8 bb = *(const bf16x8*)&Bt[nf * 16 + (lane & 15)][kt * 32 + kq];
            acc2[0][nf] = __builtin_amdgcn_mfma_f32_16x16x32_bf16(a0, bb, acc2[0][nf], 0, 0, 0);
            acc2[1][nf] = __builtin_amdgcn_mfma_f32_16x16x32_bf16(a1, bb, acc2[1][nf], 0, 0, 0);
        }
        if (kt < 7) {
            *(uint4*)&Wt[(kt + 1) & 1][srow][shalf * 16]     = w0;
            *(uint4*)&Wt[(kt + 1) & 1][srow][shalf * 16 + 8] = w1;
        }
        __syncthreads();
    }
    // ---- epilogue: BN + ReLU + store ----
    #pragma unroll
    for (int f = 0; f < 2; ++f) {
        #pragma unroll
        for (int nf = 0; nf < 4; ++nf) {
            #pragma unroll
            for (int r = 0; r < 4; ++r) {
                int o = wv * 32 + f * 16 + (lane >> 4) * 4 + r;
                float y = acc2[f][nf][r] * ssb[o] + ssb[256 + o];
                out[((size_t)(b * 256 + o)) * P_TOT + pbase + nf * 16 + (lane & 15)]
                    = fmaxf(y, 0.0f);
            }
        }
    }
}

extern "C" void kernel_launch(void* const* d_in, const int* in_sizes, int n_in,
                              void* d_out, int out_size, void* d_ws, size_t ws_size,
                              hipStream_t stream) {
    const float* feats = (const float*)d_in[0];
    const float* intr  = (const float*)d_in[1];
    const float* extr  = (const float*)d_in[2];
    const float* convw = (const float*)d_in[3];
    const float* convb = (const float*)d_in[4];
    const float* gamma = (const float*)d_in[5];
    const float* beta  = (const float*)d_in[6];
    const float* mean  = (const float*)d_in[7];
    const float* var   = (const float*)d_in[8];

    char* ws = (char*)d_ws;
    float*          params = (float*)(ws + 0);              // 1152 B
    float*          sb     = (float*)(ws + 2048);           // 2 KB
    unsigned short* wbf    = (unsigned short*)(ws + 4096);  // 128 KB
    unsigned short* ft     = (unsigned short*)(ws + 135168);// 17.0 MB
    float* out = (float*)d_out;

    hipLaunchKernelGGL(prep_kernel, dim3(256), dim3(256), 0, stream,
                       intr, extr, convw, convb, gamma, beta, mean, var, params, sb, wbf);
    hipLaunchKernelGGL(transpose_kernel, dim3(696), dim3(256), 0, stream, feats, ft);
    hipLaunchKernelGGL(fused_kernel, dim3(625, 4), dim3(512), 0, stream,
                       ft, params, wbf, sb, out);
}